// Round 9
// baseline (472.579 us; speedup 1.0000x reference)
//
#include <hip/hip_runtime.h>
#include <math.h>

#define N_NODES 50000
#define N_EDGES 1600000
#define C 64
#define OUTC 7

#define NB 196         // coarse buckets: dst >> 8  (49999>>8 = 195)
#define BCAP 10240     // bucket capacity (mean 8192, sigma ~90)
#define CHUNK 4096     // edges per phase-1 workgroup

typedef float nfloat4 __attribute__((ext_vector_type(4)));  // nt-store-compatible

// ---------------- CSR build, phase 1: coarse binning ----------------
// Pack edge as (dst<<16)|src (both < 65536). bucket = v >> 24 (= dst>>8).
__global__ __launch_bounds__(256) void bin_kernel(const int* __restrict__ src,
                                                  const int* __restrict__ dst,
                                                  unsigned int* __restrict__ buckets,
                                                  int* __restrict__ gcursor) {
    __shared__ unsigned int staged[CHUNK];          // 16 KB
    __shared__ int hist[NB], scanb[NB], cur[NB], baseb[NB];
    const int tid = threadIdx.x;
    const int base = blockIdx.x * CHUNK;
    int n = N_EDGES - base; if (n > CHUNK) n = CHUNK;  // multiple of 4

    for (int b = tid; b < NB; b += 256) { hist[b] = 0; cur[b] = 0; }
    __syncthreads();

    const int4* src4 = (const int4*)(src + base);
    const int4* dst4 = (const int4*)(dst + base);
    unsigned int v[16];
    int nv = n >> 2;
#pragma unroll
    for (int k = 0; k < 4; ++k) {
        int i4 = k * 256 + tid;
        if (i4 < nv) {
            int4 s4 = src4[i4];
            int4 d4 = dst4[i4];
            unsigned int d0 = (unsigned int)d4.x, d1 = (unsigned int)d4.y;
            unsigned int d2 = (unsigned int)d4.z, d3 = (unsigned int)d4.w;
            v[k * 4 + 0] = (d0 << 16) | (unsigned int)s4.x;
            v[k * 4 + 1] = (d1 << 16) | (unsigned int)s4.y;
            v[k * 4 + 2] = (d2 << 16) | (unsigned int)s4.z;
            v[k * 4 + 3] = (d3 << 16) | (unsigned int)s4.w;
            atomicAdd(&hist[d0 >> 8], 1);
            atomicAdd(&hist[d1 >> 8], 1);
            atomicAdd(&hist[d2 >> 8], 1);
            atomicAdd(&hist[d3 >> 8], 1);
        }
    }
    __syncthreads();
    if (tid == 0) {
        int run = 0;
        for (int b = 0; b < NB; ++b) { scanb[b] = run; run += hist[b]; }
    }
    __syncthreads();
#pragma unroll
    for (int k = 0; k < 4; ++k) {
        int i4 = k * 256 + tid;
        if (i4 < nv) {
#pragma unroll
            for (int q = 0; q < 4; ++q) {
                unsigned int w = v[k * 4 + q];
                int b = w >> 24;
                int p = scanb[b] + atomicAdd(&cur[b], 1);
                staged[p] = w;
            }
        }
    }
    __syncthreads();
    if (tid < NB) baseb[tid] = atomicAdd(&gcursor[tid], hist[tid]);
    __syncthreads();
    for (int i = tid; i < n; i += 256) {
        unsigned int w = staged[i];
        int b = w >> 24;
        buckets[(size_t)b * BCAP + baseb[b] + (i - scanb[b])] = w;
    }
}

// ---------------- CSR build, phase 2: per-bucket local CSR ----------------
__global__ __launch_bounds__(256) void build_csr(const unsigned int* __restrict__ buckets,
                                                 const int* __restrict__ gcursor,
                                                 unsigned int* __restrict__ csr,
                                                 int* __restrict__ off) {
    __shared__ int hist[256], part[256], offx[256], cur[256];
    __shared__ int gl[NB];
    __shared__ int s_cnt, s_base;
    const int tid = threadIdx.x;
    const int b = blockIdx.x;

    hist[tid] = 0;
    cur[tid] = 0;
    if (tid < NB) gl[tid] = gcursor[tid];
    __syncthreads();
    if (tid == 0) {
        int bs = 0;
        for (int i = 0; i < b; ++i) bs += gl[i];
        s_base = bs;
        s_cnt = gl[b];
    }
    __syncthreads();
    const int cnt = s_cnt;
    const int gbase = s_base;
    const unsigned int* bk = buckets + (size_t)b * BCAP;

    for (int i = tid; i < cnt; i += 256) {
        atomicAdd(&hist[(bk[i] >> 16) & 255], 1);
    }
    __syncthreads();
    part[tid] = hist[tid];
    __syncthreads();
    for (int d = 1; d < 256; d <<= 1) {
        int t = (tid >= d) ? part[tid - d] : 0;
        __syncthreads();
        part[tid] += t;
        __syncthreads();
    }
    offx[tid] = (tid == 0) ? 0 : part[tid - 1];
    __syncthreads();
    int node = b * 256 + tid;
    if (node < N_NODES) off[node] = gbase + offx[tid];
    if (b == NB - 1 && tid == 0) off[N_NODES] = gbase + cnt;
    for (int i = tid; i < cnt; i += 256) {
        unsigned int w = bk[i];
        int dl = (w >> 16) & 255;
        int p = offx[dl] + atomicAdd(&cur[dl], 1);
        csr[gbase + p] = w & 0xFFFFu;
    }
}

// ---------------- dense linears ----------------

// 4 waves/block; wave owns channels [wave*16, wave*16+16), lane = row.
__global__ __launch_bounds__(256) void linear64_split(const float* __restrict__ x,
                                                      const float* __restrict__ W,
                                                      float* __restrict__ out) {
    const int wave = threadIdx.x >> 6;
    const int lane = threadIdx.x & 63;
    const int r = blockIdx.x * 64 + lane;
    if (r >= N_NODES) return;
    float4 xr[16];
    const float4* xp = (const float4*)(x + (size_t)r * 64);
#pragma unroll
    for (int j = 0; j < 16; ++j) xr[j] = xp[j];
    const float* xf = (const float*)xr;

    const float* Wp = W + wave * 16 * 64;   // wave-uniform
    float4* op = (float4*)(out + (size_t)r * 64 + wave * 16);
    for (int c0 = 0; c0 < 16; c0 += 8) {
        float acc[8] = {0.f, 0.f, 0.f, 0.f, 0.f, 0.f, 0.f, 0.f};
#pragma unroll
        for (int k = 0; k < 64; ++k) {
            float xv = xf[k];
#pragma unroll
            for (int j = 0; j < 8; ++j)
                acc[j] += xv * Wp[(c0 + j) * 64 + k];  // uniform address
        }
        op[c0 >> 2]       = make_float4(acc[0], acc[1], acc[2], acc[3]);
        op[(c0 >> 2) + 1] = make_float4(acc[4], acc[5], acc[6], acc[7]);
    }
}

// k-split across lane pairs: even lane k in [0,32), odd k in [32,64).
__global__ __launch_bounds__(256) void linear7_rows(const float* __restrict__ x,
                                                    const float* __restrict__ W,
                                                    float* __restrict__ out) {
    int gid = blockIdx.x * 256 + threadIdx.x;
    int r = gid >> 1;
    int half = gid & 1;
    if (r >= N_NODES) return;
    float4 xr[8];
    const float4* xp = (const float4*)(x + (size_t)r * 64 + half * 32);
#pragma unroll
    for (int j = 0; j < 8; ++j) xr[j] = xp[j];
    const float* xf = (const float*)xr;

    float acc[7] = {0.f, 0.f, 0.f, 0.f, 0.f, 0.f, 0.f};
#pragma unroll
    for (int k = 0; k < 32; ++k) {
        float xv = xf[k];
#pragma unroll
        for (int j = 0; j < 7; ++j)
            acc[j] += xv * W[j * 64 + half * 32 + k];
    }
#pragma unroll
    for (int j = 0; j < 7; ++j) acc[j] += __shfl_xor(acc[j], 1, 64);
    if (half == 0) {
        float4* op = (float4*)(out + (size_t)r * 8);
        op[0] = make_float4(acc[0], acc[1], acc[2], acc[3]);
        op[1] = make_float4(acc[4], acc[5], acc[6], 0.f);
    }
}

// ---------------- gather aggregation: channel-quarter x XCD affinity --------

// Each wave: one (node, channel-quarter). quarter = (blockIdx%8)>>1 so each
// XCD (blockIdx%8 empirical mapping) touches only a 50000x16ch = 3.2 MB slice
// of t -> L2-resident. csr/off are nontemporal (streamed, don't evict slice).
// Lane map: slot = lane>>2 (16 edge slots), ch = lane&3 (float4 within the
// 16-ch quarter). One loop iteration covers 16 edges.
__global__ __launch_bounds__(1024) void gather16(const int* __restrict__ off,
                                                 const unsigned int* __restrict__ csr_src,
                                                 const float* __restrict__ t,
                                                 const float* __restrict__ b,
                                                 float* __restrict__ out,
                                                 int do_relu) {
    const int blk = blockIdx.x;
    const int q = (blk & 7) >> 1;            // channel quarter, pinned per XCD
    const int wave = threadIdx.x >> 6;       // 0..15
    const int k = (blk >> 3) * 2 + (blk & 1);  // node-group within quarter
    const int node = k * 16 + wave;
    if (node >= N_NODES) return;
    const int lane = threadIdx.x & 63;
    const int slot = lane >> 2;
    const int ch   = lane & 3;
    int e0 = __builtin_nontemporal_load(off + node);
    int e1 = __builtin_nontemporal_load(off + node + 1);
    const float4* t4 = (const float4*)t + q * 4 + ch;
    float sx = 0.f, sy = 0.f, sz = 0.f, sw = 0.f;
    for (int e = e0 + slot; e < e1; e += 16) {
        unsigned int s = __builtin_nontemporal_load(csr_src + e);
        float4 v = t4[(size_t)s * 16];
        sx += v.x; sy += v.y; sz += v.z; sw += v.w;
    }
    // fold 16 slots (lane bits 2..5); ch bits preserved
    sx += __shfl_xor(sx, 4, 64);  sy += __shfl_xor(sy, 4, 64);
    sz += __shfl_xor(sz, 4, 64);  sw += __shfl_xor(sw, 4, 64);
    sx += __shfl_xor(sx, 8, 64);  sy += __shfl_xor(sy, 8, 64);
    sz += __shfl_xor(sz, 8, 64);  sw += __shfl_xor(sw, 8, 64);
    sx += __shfl_xor(sx, 16, 64); sy += __shfl_xor(sy, 16, 64);
    sz += __shfl_xor(sz, 16, 64); sw += __shfl_xor(sw, 16, 64);
    sx += __shfl_xor(sx, 32, 64); sy += __shfl_xor(sy, 32, 64);
    sz += __shfl_xor(sz, 32, 64); sw += __shfl_xor(sw, 32, 64);
    if (lane < 4) {
        const float4 bb = ((const float4*)b)[q * 4 + ch];
        nfloat4 r;
        r.x = sx + bb.x; r.y = sy + bb.y; r.z = sz + bb.z; r.w = sw + bb.w;
        if (do_relu) {
            r.x = fmaxf(r.x, 0.f); r.y = fmaxf(r.y, 0.f);
            r.z = fmaxf(r.z, 0.f); r.w = fmaxf(r.w, 0.f);
        }
        nfloat4* dst = (nfloat4*)(out + (size_t)node * 64 + q * 16) + ch;
        __builtin_nontemporal_store(r, dst);
    }
}

// 7-ch gather + bias + log_softmax. slot = lane>>1 (32 edge slots), h = lane&1.
__global__ __launch_bounds__(256) void gather7_lsm(const int* __restrict__ off,
                                                   const unsigned int* __restrict__ csr_src,
                                                   const float* __restrict__ t3,
                                                   const float* __restrict__ b,
                                                   float* __restrict__ out) {
    int node = blockIdx.x * 4 + (threadIdx.x >> 6);
    if (node >= N_NODES) return;
    const int lane = threadIdx.x & 63;
    const int slot = lane >> 1;
    const int h    = lane & 1;
    int e0 = off[node], e1 = off[node + 1];
    const float4* t4 = (const float4*)t3;
    float sx = 0.f, sy = 0.f, sz = 0.f, sw = 0.f;
    for (int e = e0 + slot; e < e1; e += 32) {
        unsigned int s = __builtin_nontemporal_load(csr_src + e);
        float4 v = t4[(size_t)s * 2 + h];
        sx += v.x; sy += v.y; sz += v.z; sw += v.w;
    }
#pragma unroll
    for (int d = 2; d <= 32; d <<= 1) {
        sx += __shfl_xor(sx, d, 64); sy += __shfl_xor(sy, d, 64);
        sz += __shfl_xor(sz, d, 64); sw += __shfl_xor(sw, d, 64);
    }
    float z0 = sx + b[h * 4 + 0];
    float z1 = sy + b[h * 4 + 1];
    float z2 = sz + b[h * 4 + 2];
    float z3 = (h == 0) ? (sw + b[3]) : -1e30f;
    float m = fmaxf(fmaxf(z0, z1), fmaxf(z2, z3));
    m = fmaxf(m, __shfl_xor(m, 1, 64));
    float ex = __expf(z0 - m) + __expf(z1 - m) + __expf(z2 - m) + __expf(z3 - m);
    ex += __shfl_xor(ex, 1, 64);
    float l = m + __logf(ex);
    if (lane < 2) {
        float* o = out + (size_t)node * 7 + h * 4;
        o[0] = z0 - l; o[1] = z1 - l; o[2] = z2 - l;
        if (h == 0) o[3] = z3 - l;
    }
}

extern "C" void kernel_launch(void* const* d_in, const int* in_sizes, int n_in,
                              void* d_out, int out_size, void* d_ws, size_t ws_size,
                              hipStream_t stream) {
    const float* x  = (const float*)d_in[0];
    const int*   ei = (const int*)d_in[1];
    const float* W1 = (const float*)d_in[2];
    const float* b1 = (const float*)d_in[3];
    const float* W2 = (const float*)d_in[4];
    const float* b2 = (const float*)d_in[5];
    const float* W3 = (const float*)d_in[6];
    const float* b3 = (const float*)d_in[7];
    float* out = (float*)d_out;

    const int* src = ei;
    const int* dst = ei + N_EDGES;

    float* A = (float*)d_ws;                       // 12.8 MB
    float* B = A + (size_t)N_NODES * C;            // 12.8 MB
    unsigned int* csr = (unsigned int*)(B + (size_t)N_NODES * C);
    int* off     = (int*)(csr + N_EDGES);          // 50001
    int* gcursor = off + N_NODES + 8;              // 196
    unsigned int* buckets = (unsigned int*)A;      // aliases A (8.03 MB)

    const int l64grid = (N_NODES + 63) / 64;       // 782 blocks x 4 waves
    const int l7grid  = (2 * N_NODES + 255) / 256; // 391
    // gather16: 16 nodes/block/quarter; per quarter need ceil(50000/16)=3125
    // blocks; x4 quarters = 12500; round up to multiple of 8 -> 12504.
    const int g16grid = 12504;
    const int n7grid  = (N_NODES + 3) / 4;

    // ---- CSR build
    (void)hipMemsetAsync(gcursor, 0, NB * sizeof(int), stream);
    bin_kernel<<<(N_EDGES + CHUNK - 1) / CHUNK, 256, 0, stream>>>(src, dst, buckets, gcursor);
    build_csr<<<NB, 256, 0, stream>>>(buckets, gcursor, csr, off);

    // ---- layer 1 (A free after build_csr)
    linear64_split<<<l64grid, 256, 0, stream>>>(x, W1, A);
    gather16<<<g16grid, 1024, 0, stream>>>(off, csr, A, b1, B, 1);

    // ---- layer 2
    linear64_split<<<l64grid, 256, 0, stream>>>(B, W2, A);
    gather16<<<g16grid, 1024, 0, stream>>>(off, csr, A, b2, B, 1);

    // ---- layer 3
    linear7_rows<<<l7grid, 256, 0, stream>>>(B, W3, A);
    gather7_lsm<<<n7grid, 256, 0, stream>>>(off, csr, A, b3, out);
}

// Round 10
// 303.058 us; speedup vs baseline: 1.5594x; 1.5594x over previous
//
#include <hip/hip_runtime.h>
#include <math.h>

#define N_NODES 50000
#define N_EDGES 1600000
#define C 64
#define OUTC 7

#define NB 196         // coarse buckets: dst >> 8  (49999>>8 = 195)
#define BCAP 10240     // bucket capacity (mean 8192, sigma ~90)
#define CHUNK 4096     // edges per phase-1 workgroup

// fp32 -> bf16 (RNE), packed pair into u32 (lo = even channel, hi = odd)
__device__ __forceinline__ unsigned int pk_bf16(float a, float b) {
    unsigned int ua = __float_as_uint(a);
    ua = (ua + 0x7FFFu + ((ua >> 16) & 1u)) >> 16;
    unsigned int ub = __float_as_uint(b);
    ub = (ub + 0x7FFFu + ((ub >> 16) & 1u)) >> 16;
    return ua | (ub << 16);
}

// ---------------- CSR build, phase 1: coarse binning ----------------
// Pack edge as (dst<<16)|src (both < 65536). bucket = v >> 24 (= dst>>8).
__global__ __launch_bounds__(256) void bin_kernel(const int* __restrict__ src,
                                                  const int* __restrict__ dst,
                                                  unsigned int* __restrict__ buckets,
                                                  int* __restrict__ gcursor) {
    __shared__ unsigned int staged[CHUNK];          // 16 KB
    __shared__ int hist[NB], scanb[NB], cur[NB], baseb[NB];
    const int tid = threadIdx.x;
    const int base = blockIdx.x * CHUNK;
    int n = N_EDGES - base; if (n > CHUNK) n = CHUNK;  // multiple of 4

    for (int b = tid; b < NB; b += 256) { hist[b] = 0; cur[b] = 0; }
    __syncthreads();

    const int4* src4 = (const int4*)(src + base);
    const int4* dst4 = (const int4*)(dst + base);
    unsigned int v[16];
    int nv = n >> 2;
#pragma unroll
    for (int k = 0; k < 4; ++k) {
        int i4 = k * 256 + tid;
        if (i4 < nv) {
            int4 s4 = src4[i4];
            int4 d4 = dst4[i4];
            unsigned int d0 = (unsigned int)d4.x, d1 = (unsigned int)d4.y;
            unsigned int d2 = (unsigned int)d4.z, d3 = (unsigned int)d4.w;
            v[k * 4 + 0] = (d0 << 16) | (unsigned int)s4.x;
            v[k * 4 + 1] = (d1 << 16) | (unsigned int)s4.y;
            v[k * 4 + 2] = (d2 << 16) | (unsigned int)s4.z;
            v[k * 4 + 3] = (d3 << 16) | (unsigned int)s4.w;
            atomicAdd(&hist[d0 >> 8], 1);
            atomicAdd(&hist[d1 >> 8], 1);
            atomicAdd(&hist[d2 >> 8], 1);
            atomicAdd(&hist[d3 >> 8], 1);
        }
    }
    __syncthreads();
    if (tid == 0) {
        int run = 0;
        for (int b = 0; b < NB; ++b) { scanb[b] = run; run += hist[b]; }
    }
    __syncthreads();
#pragma unroll
    for (int k = 0; k < 4; ++k) {
        int i4 = k * 256 + tid;
        if (i4 < nv) {
#pragma unroll
            for (int q = 0; q < 4; ++q) {
                unsigned int w = v[k * 4 + q];
                int b = w >> 24;
                int p = scanb[b] + atomicAdd(&cur[b], 1);
                staged[p] = w;
            }
        }
    }
    __syncthreads();
    if (tid < NB) baseb[tid] = atomicAdd(&gcursor[tid], hist[tid]);
    __syncthreads();
    for (int i = tid; i < n; i += 256) {
        unsigned int w = staged[i];
        int b = w >> 24;
        buckets[(size_t)b * BCAP + baseb[b] + (i - scanb[b])] = w;
    }
}

// ---------------- CSR build, phase 2: per-bucket local CSR ----------------
__global__ __launch_bounds__(256) void build_csr(const unsigned int* __restrict__ buckets,
                                                 const int* __restrict__ gcursor,
                                                 unsigned int* __restrict__ csr,
                                                 int* __restrict__ off) {
    __shared__ int hist[256], part[256], offx[256], cur[256];
    __shared__ int gl[NB];
    __shared__ int s_cnt, s_base;
    const int tid = threadIdx.x;
    const int b = blockIdx.x;

    hist[tid] = 0;
    cur[tid] = 0;
    if (tid < NB) gl[tid] = gcursor[tid];
    __syncthreads();
    if (tid == 0) {
        int bs = 0;
        for (int i = 0; i < b; ++i) bs += gl[i];
        s_base = bs;
        s_cnt = gl[b];
    }
    __syncthreads();
    const int cnt = s_cnt;
    const int gbase = s_base;
    const unsigned int* bk = buckets + (size_t)b * BCAP;

    for (int i = tid; i < cnt; i += 256) {
        atomicAdd(&hist[(bk[i] >> 16) & 255], 1);
    }
    __syncthreads();
    part[tid] = hist[tid];
    __syncthreads();
    for (int d = 1; d < 256; d <<= 1) {
        int t = (tid >= d) ? part[tid - d] : 0;
        __syncthreads();
        part[tid] += t;
        __syncthreads();
    }
    offx[tid] = (tid == 0) ? 0 : part[tid - 1];
    __syncthreads();
    int node = b * 256 + tid;
    if (node < N_NODES) off[node] = gbase + offx[tid];
    if (b == NB - 1 && tid == 0) off[N_NODES] = gbase + cnt;
    for (int i = tid; i < cnt; i += 256) {
        unsigned int w = bk[i];
        int dl = (w >> 16) & 255;
        int p = offx[dl] + atomicAdd(&cur[dl], 1);
        csr[gbase + p] = w & 0xFFFFu;
    }
}

// ---------------- dense linears ----------------

// 4 waves/block; wave owns channels [wave*16, wave*16+16), lane = row.
// Output written as packed bf16 rows (64 x bf16 = 32 u32 per row).
__global__ __launch_bounds__(256) void linear64_bf16(const float* __restrict__ x,
                                                     const float* __restrict__ W,
                                                     unsigned int* __restrict__ tb) {
    const int wave = threadIdx.x >> 6;
    const int lane = threadIdx.x & 63;
    const int r = blockIdx.x * 64 + lane;
    if (r >= N_NODES) return;
    float4 xr[16];
    const float4* xp = (const float4*)(x + (size_t)r * 64);
#pragma unroll
    for (int j = 0; j < 16; ++j) xr[j] = xp[j];
    const float* xf = (const float*)xr;

    const float* Wp = W + wave * 16 * 64;   // wave-uniform
    unsigned int* orow = tb + (size_t)r * 32 + wave * 8;  // 8 u32 = 16 bf16
    for (int c0 = 0; c0 < 16; c0 += 8) {
        float acc[8] = {0.f, 0.f, 0.f, 0.f, 0.f, 0.f, 0.f, 0.f};
#pragma unroll
        for (int k = 0; k < 64; ++k) {
            float xv = xf[k];
#pragma unroll
            for (int j = 0; j < 8; ++j)
                acc[j] += xv * Wp[(c0 + j) * 64 + k];  // uniform address
        }
        uint4 w;
        w.x = pk_bf16(acc[0], acc[1]);
        w.y = pk_bf16(acc[2], acc[3]);
        w.z = pk_bf16(acc[4], acc[5]);
        w.w = pk_bf16(acc[6], acc[7]);
        ((uint4*)orow)[c0 >> 3] = w;
    }
}

// k-split across lane pairs: even lane k in [0,32), odd k in [32,64). fp32 out.
__global__ __launch_bounds__(256) void linear7_rows(const float* __restrict__ x,
                                                    const float* __restrict__ W,
                                                    float* __restrict__ out) {
    int gid = blockIdx.x * 256 + threadIdx.x;
    int r = gid >> 1;
    int half = gid & 1;
    if (r >= N_NODES) return;
    float4 xr[8];
    const float4* xp = (const float4*)(x + (size_t)r * 64 + half * 32);
#pragma unroll
    for (int j = 0; j < 8; ++j) xr[j] = xp[j];
    const float* xf = (const float*)xr;

    float acc[7] = {0.f, 0.f, 0.f, 0.f, 0.f, 0.f, 0.f};
#pragma unroll
    for (int k = 0; k < 32; ++k) {
        float xv = xf[k];
#pragma unroll
        for (int j = 0; j < 7; ++j)
            acc[j] += xv * W[j * 64 + half * 32 + k];
    }
#pragma unroll
    for (int j = 0; j < 7; ++j) acc[j] += __shfl_xor(acc[j], 1, 64);
    if (half == 0) {
        float4* op = (float4*)(out + (size_t)r * 8);
        op[0] = make_float4(acc[0], acc[1], acc[2], acc[3]);
        op[1] = make_float4(acc[4], acc[5], acc[6], 0.f);
    }
}

// ---------------- gather aggregation: bf16 table, fp32 accumulate ----------

// Lane map: slot = lane>>3 (8 edge slots), ch8 = lane&7 (uint4 = 8 bf16 ch).
// One dwordx4 load = 8 channels of one edge row; 16 edges per loop iteration
// (2 independent loads). Fold slots with 3 shfl_xor rounds; lanes 0..7 write
// 8 fp32 channels each (full 256 B row).
__global__ __launch_bounds__(256) void gather64b(const int* __restrict__ off,
                                                 const unsigned int* __restrict__ csr_src,
                                                 const unsigned int* __restrict__ tb,
                                                 const float* __restrict__ b,
                                                 float* __restrict__ out,
                                                 int do_relu) {
    int node = blockIdx.x * 4 + (threadIdx.x >> 6);
    if (node >= N_NODES) return;
    const int lane = threadIdx.x & 63;
    const int slot = lane >> 3;
    const int ch8  = lane & 7;
    int e0 = off[node], e1 = off[node + 1];
    const uint4* t4 = (const uint4*)tb;
    float s[8] = {0.f, 0.f, 0.f, 0.f, 0.f, 0.f, 0.f, 0.f};
    for (int e = e0; e < e1; e += 16) {
        int i0 = e + slot;
        int i1 = e + 8 + slot;
        bool p0 = i0 < e1, p1 = i1 < e1;
        unsigned int a0 = csr_src[p0 ? i0 : e];
        unsigned int a1 = csr_src[p1 ? i1 : e];
        uint4 v0 = t4[(size_t)a0 * 8 + ch8];
        uint4 v1 = t4[(size_t)a1 * 8 + ch8];
        if (p0) {
            s[0] += __uint_as_float(v0.x << 16);
            s[1] += __uint_as_float(v0.x & 0xFFFF0000u);
            s[2] += __uint_as_float(v0.y << 16);
            s[3] += __uint_as_float(v0.y & 0xFFFF0000u);
            s[4] += __uint_as_float(v0.z << 16);
            s[5] += __uint_as_float(v0.z & 0xFFFF0000u);
            s[6] += __uint_as_float(v0.w << 16);
            s[7] += __uint_as_float(v0.w & 0xFFFF0000u);
        }
        if (p1) {
            s[0] += __uint_as_float(v1.x << 16);
            s[1] += __uint_as_float(v1.x & 0xFFFF0000u);
            s[2] += __uint_as_float(v1.y << 16);
            s[3] += __uint_as_float(v1.y & 0xFFFF0000u);
            s[4] += __uint_as_float(v1.z << 16);
            s[5] += __uint_as_float(v1.z & 0xFFFF0000u);
            s[6] += __uint_as_float(v1.w << 16);
            s[7] += __uint_as_float(v1.w & 0xFFFF0000u);
        }
    }
    // fold the 8 slots (lane bits 3..5); ch8 bits preserved
#pragma unroll
    for (int d = 8; d <= 32; d <<= 1) {
#pragma unroll
        for (int j = 0; j < 8; ++j) s[j] += __shfl_xor(s[j], d, 64);
    }
    if (lane < 8) {
        const float4 b0 = ((const float4*)b)[ch8 * 2];
        const float4 b1 = ((const float4*)b)[ch8 * 2 + 1];
        float4 r0, r1;
        r0.x = s[0] + b0.x; r0.y = s[1] + b0.y; r0.z = s[2] + b0.z; r0.w = s[3] + b0.w;
        r1.x = s[4] + b1.x; r1.y = s[5] + b1.y; r1.z = s[6] + b1.z; r1.w = s[7] + b1.w;
        if (do_relu) {
            r0.x = fmaxf(r0.x, 0.f); r0.y = fmaxf(r0.y, 0.f);
            r0.z = fmaxf(r0.z, 0.f); r0.w = fmaxf(r0.w, 0.f);
            r1.x = fmaxf(r1.x, 0.f); r1.y = fmaxf(r1.y, 0.f);
            r1.z = fmaxf(r1.z, 0.f); r1.w = fmaxf(r1.w, 0.f);
        }
        float4* orow = (float4*)(out + (size_t)node * 64 + ch8 * 8);
        orow[0] = r0;
        orow[1] = r1;
    }
}

// 7-ch gather + bias + log_softmax (fp32 t3). slot = lane>>1, h = lane&1.
__global__ __launch_bounds__(256) void gather7_lsm(const int* __restrict__ off,
                                                   const unsigned int* __restrict__ csr_src,
                                                   const float* __restrict__ t3,
                                                   const float* __restrict__ b,
                                                   float* __restrict__ out) {
    int node = blockIdx.x * 4 + (threadIdx.x >> 6);
    if (node >= N_NODES) return;
    const int lane = threadIdx.x & 63;
    const int slot = lane >> 1;
    const int h    = lane & 1;
    int e0 = off[node], e1 = off[node + 1];
    const float4* t4 = (const float4*)t3;
    float sx = 0.f, sy = 0.f, sz = 0.f, sw = 0.f;
    for (int e = e0 + slot; e < e1; e += 32) {
        unsigned int s = csr_src[e];
        float4 v = t4[(size_t)s * 2 + h];
        sx += v.x; sy += v.y; sz += v.z; sw += v.w;
    }
#pragma unroll
    for (int d = 2; d <= 32; d <<= 1) {
        sx += __shfl_xor(sx, d, 64); sy += __shfl_xor(sy, d, 64);
        sz += __shfl_xor(sz, d, 64); sw += __shfl_xor(sw, d, 64);
    }
    float z0 = sx + b[h * 4 + 0];
    float z1 = sy + b[h * 4 + 1];
    float z2 = sz + b[h * 4 + 2];
    float z3 = (h == 0) ? (sw + b[3]) : -1e30f;
    float m = fmaxf(fmaxf(z0, z1), fmaxf(z2, z3));
    m = fmaxf(m, __shfl_xor(m, 1, 64));
    float ex = __expf(z0 - m) + __expf(z1 - m) + __expf(z2 - m) + __expf(z3 - m);
    ex += __shfl_xor(ex, 1, 64);
    float l = m + __logf(ex);
    if (lane < 2) {
        float* o = out + (size_t)node * 7 + h * 4;
        o[0] = z0 - l; o[1] = z1 - l; o[2] = z2 - l;
        if (h == 0) o[3] = z3 - l;
    }
}

extern "C" void kernel_launch(void* const* d_in, const int* in_sizes, int n_in,
                              void* d_out, int out_size, void* d_ws, size_t ws_size,
                              hipStream_t stream) {
    const float* x  = (const float*)d_in[0];
    const int*   ei = (const int*)d_in[1];
    const float* W1 = (const float*)d_in[2];
    const float* b1 = (const float*)d_in[3];
    const float* W2 = (const float*)d_in[4];
    const float* b2 = (const float*)d_in[5];
    const float* W3 = (const float*)d_in[6];
    const float* b3 = (const float*)d_in[7];
    float* out = (float*)d_out;

    const int* src = ei;
    const int* dst = ei + N_EDGES;

    // workspace: A region (12.8 MB) holds, in sequence: phase-1 buckets
    // (8.03 MB, dead after build_csr) -> bf16 feature table (6.4 MB) for
    // layers 1-2 -> fp32 stride-8 t3 (1.6 MB) for layer 3.
    float* A = (float*)d_ws;                       // 12.8 MB
    float* B = A + (size_t)N_NODES * C;            // 12.8 MB (fp32 h buffer)
    unsigned int* csr = (unsigned int*)(B + (size_t)N_NODES * C);
    int* off     = (int*)(csr + N_EDGES);          // 50001
    int* gcursor = off + N_NODES + 8;              // 196
    unsigned int* buckets = (unsigned int*)A;      // aliases A
    unsigned int* Abf     = (unsigned int*)A;      // bf16 table view

    const int l64grid = (N_NODES + 63) / 64;       // 782 blocks x 4 waves
    const int l7grid  = (2 * N_NODES + 255) / 256; // 391
    const int ngrid   = (N_NODES + 3) / 4;         // 12500

    // ---- CSR build
    (void)hipMemsetAsync(gcursor, 0, NB * sizeof(int), stream);
    bin_kernel<<<(N_EDGES + CHUNK - 1) / CHUNK, 256, 0, stream>>>(src, dst, buckets, gcursor);
    build_csr<<<NB, 256, 0, stream>>>(buckets, gcursor, csr, off);

    // ---- layer 1 (A free after build_csr)
    linear64_bf16<<<l64grid, 256, 0, stream>>>(x, W1, Abf);
    gather64b<<<ngrid, 256, 0, stream>>>(off, csr, Abf, b1, B, 1);

    // ---- layer 2
    linear64_bf16<<<l64grid, 256, 0, stream>>>(B, W2, Abf);
    gather64b<<<ngrid, 256, 0, stream>>>(off, csr, Abf, b2, B, 1);

    // ---- layer 3 (fp32 staging, stride-8)
    linear7_rows<<<l7grid, 256, 0, stream>>>(B, W3, A);
    gather7_lsm<<<ngrid, 256, 0, stream>>>(off, csr, A, b3, out);
}

// Round 11
// 300.203 us; speedup vs baseline: 1.5742x; 1.0095x over previous
//
#include <hip/hip_runtime.h>
#include <math.h>

#define N_NODES 50000
#define N_EDGES 1600000
#define C 64
#define OUTC 7

#define NB 196         // coarse buckets: dst >> 8  (49999>>8 = 195)
#define BCAP 10240     // bucket capacity (mean 8192, sigma ~90)
#define CHUNK 4096     // edges per phase-1 workgroup

// fp32 -> bf16 (RNE), packed pair into u32 (lo = even channel, hi = odd)
__device__ __forceinline__ unsigned int pk_bf16(float a, float b) {
    unsigned int ua = __float_as_uint(a);
    ua = (ua + 0x7FFFu + ((ua >> 16) & 1u)) >> 16;
    unsigned int ub = __float_as_uint(b);
    ub = (ub + 0x7FFFu + ((ub >> 16) & 1u)) >> 16;
    return ua | (ub << 16);
}

// Force a pointer into SGPRs (per-wave readfirstlane) so uniform-indexed
// loads scalarize to s_load (K$ pipe) instead of per-lane VMEM.
__device__ __forceinline__ const float* uniform_ptr(const float* p) {
    unsigned long long v = (unsigned long long)p;
    unsigned int lo = __builtin_amdgcn_readfirstlane((unsigned int)v);
    unsigned int hi = __builtin_amdgcn_readfirstlane((unsigned int)(v >> 32));
    return (const float*)((((unsigned long long)hi) << 32) | (unsigned long long)lo);
}

// ---------------- CSR build, phase 1: coarse binning ----------------
// Pack edge as (dst<<16)|src (both < 65536). bucket = v >> 24 (= dst>>8).
__global__ __launch_bounds__(256) void bin_kernel(const int* __restrict__ src,
                                                  const int* __restrict__ dst,
                                                  unsigned int* __restrict__ buckets,
                                                  int* __restrict__ gcursor) {
    __shared__ unsigned int staged[CHUNK];          // 16 KB
    __shared__ int hist[NB], scanb[NB], cur[NB], baseb[NB];
    const int tid = threadIdx.x;
    const int base = blockIdx.x * CHUNK;
    int n = N_EDGES - base; if (n > CHUNK) n = CHUNK;  // multiple of 4

    for (int b = tid; b < NB; b += 256) { hist[b] = 0; cur[b] = 0; }
    __syncthreads();

    const int4* src4 = (const int4*)(src + base);
    const int4* dst4 = (const int4*)(dst + base);
    unsigned int v[16];
    int nv = n >> 2;
#pragma unroll
    for (int k = 0; k < 4; ++k) {
        int i4 = k * 256 + tid;
        if (i4 < nv) {
            int4 s4 = src4[i4];
            int4 d4 = dst4[i4];
            unsigned int d0 = (unsigned int)d4.x, d1 = (unsigned int)d4.y;
            unsigned int d2 = (unsigned int)d4.z, d3 = (unsigned int)d4.w;
            v[k * 4 + 0] = (d0 << 16) | (unsigned int)s4.x;
            v[k * 4 + 1] = (d1 << 16) | (unsigned int)s4.y;
            v[k * 4 + 2] = (d2 << 16) | (unsigned int)s4.z;
            v[k * 4 + 3] = (d3 << 16) | (unsigned int)s4.w;
            atomicAdd(&hist[d0 >> 8], 1);
            atomicAdd(&hist[d1 >> 8], 1);
            atomicAdd(&hist[d2 >> 8], 1);
            atomicAdd(&hist[d3 >> 8], 1);
        }
    }
    __syncthreads();
    if (tid == 0) {
        int run = 0;
        for (int b = 0; b < NB; ++b) { scanb[b] = run; run += hist[b]; }
    }
    __syncthreads();
#pragma unroll
    for (int k = 0; k < 4; ++k) {
        int i4 = k * 256 + tid;
        if (i4 < nv) {
#pragma unroll
            for (int q = 0; q < 4; ++q) {
                unsigned int w = v[k * 4 + q];
                int b = w >> 24;
                int p = scanb[b] + atomicAdd(&cur[b], 1);
                staged[p] = w;
            }
        }
    }
    __syncthreads();
    if (tid < NB) baseb[tid] = atomicAdd(&gcursor[tid], hist[tid]);
    __syncthreads();
    for (int i = tid; i < n; i += 256) {
        unsigned int w = staged[i];
        int b = w >> 24;
        buckets[(size_t)b * BCAP + baseb[b] + (i - scanb[b])] = w;
    }
}

// ---------------- CSR build, phase 2: per-bucket local CSR ----------------
__global__ __launch_bounds__(256) void build_csr(const unsigned int* __restrict__ buckets,
                                                 const int* __restrict__ gcursor,
                                                 unsigned int* __restrict__ csr,
                                                 int* __restrict__ off) {
    __shared__ int hist[256], part[256], offx[256], cur[256];
    __shared__ int gl[NB];
    __shared__ int s_cnt, s_base;
    const int tid = threadIdx.x;
    const int b = blockIdx.x;

    hist[tid] = 0;
    cur[tid] = 0;
    if (tid < NB) gl[tid] = gcursor[tid];
    __syncthreads();
    if (tid == 0) {
        int bs = 0;
        for (int i = 0; i < b; ++i) bs += gl[i];
        s_base = bs;
        s_cnt = gl[b];
    }
    __syncthreads();
    const int cnt = s_cnt;
    const int gbase = s_base;
    const unsigned int* bk = buckets + (size_t)b * BCAP;

    for (int i = tid; i < cnt; i += 256) {
        atomicAdd(&hist[(bk[i] >> 16) & 255], 1);
    }
    __syncthreads();
    part[tid] = hist[tid];
    __syncthreads();
    for (int d = 1; d < 256; d <<= 1) {
        int t = (tid >= d) ? part[tid - d] : 0;
        __syncthreads();
        part[tid] += t;
        __syncthreads();
    }
    offx[tid] = (tid == 0) ? 0 : part[tid - 1];
    __syncthreads();
    int node = b * 256 + tid;
    if (node < N_NODES) off[node] = gbase + offx[tid];
    if (b == NB - 1 && tid == 0) off[N_NODES] = gbase + cnt;
    for (int i = tid; i < cnt; i += 256) {
        unsigned int w = bk[i];
        int dl = (w >> 16) & 255;
        int p = offx[dl] + atomicAdd(&cur[dl], 1);
        csr[gbase + p] = w & 0xFFFFu;
    }
}

// ---------------- dense linears ----------------

// 4 waves/block; wave owns channels [wave*16, wave*16+16), lane = row.
// W pointer is readfirstlane'd -> provably wave-uniform -> s_load (K$ pipe).
// Output written as packed bf16 rows (64 x bf16 = 32 u32 per row).
__global__ __launch_bounds__(256) void linear64_bf16(const float* __restrict__ x,
                                                     const float* __restrict__ W,
                                                     unsigned int* __restrict__ tb) {
    const int wave = threadIdx.x >> 6;
    const int lane = threadIdx.x & 63;
    const int r = blockIdx.x * 64 + lane;
    if (r >= N_NODES) return;
    float4 xr[16];
    const float4* xp = (const float4*)(x + (size_t)r * 64);
#pragma unroll
    for (int j = 0; j < 16; ++j) xr[j] = xp[j];
    const float* xf = (const float*)xr;

    const float* Wp = uniform_ptr(W + wave * 16 * 64);  // SGPR base -> s_load
    unsigned int* orow = tb + (size_t)r * 32 + wave * 8;  // 8 u32 = 16 bf16
    for (int c0 = 0; c0 < 16; c0 += 8) {
        float acc[8] = {0.f, 0.f, 0.f, 0.f, 0.f, 0.f, 0.f, 0.f};
#pragma unroll
        for (int k = 0; k < 64; ++k) {
            float xv = xf[k];
#pragma unroll
            for (int j = 0; j < 8; ++j)
                acc[j] += xv * Wp[(c0 + j) * 64 + k];  // uniform -> s_load
        }
        uint4 w;
        w.x = pk_bf16(acc[0], acc[1]);
        w.y = pk_bf16(acc[2], acc[3]);
        w.z = pk_bf16(acc[4], acc[5]);
        w.w = pk_bf16(acc[6], acc[7]);
        ((uint4*)orow)[c0 >> 3] = w;
    }
}

// Thread-per-row, fully-uniform W3 (kernel arg) -> auto-scalarized s_loads.
// 448 FMA/thread; W3 = 1.75 KB, K$-resident. Writes stride-8 padded rows.
__global__ __launch_bounds__(128) void linear7_rows(const float* __restrict__ x,
                                                    const float* __restrict__ W,
                                                    float* __restrict__ out) {
    int r = blockIdx.x * 128 + threadIdx.x;
    if (r >= N_NODES) return;
    float4 xr[16];
    const float4* xp = (const float4*)(x + (size_t)r * 64);
#pragma unroll
    for (int j = 0; j < 16; ++j) xr[j] = xp[j];
    const float* xf = (const float*)xr;

    float acc[7] = {0.f, 0.f, 0.f, 0.f, 0.f, 0.f, 0.f};
#pragma unroll
    for (int k = 0; k < 64; ++k) {
        float xv = xf[k];
#pragma unroll
        for (int j = 0; j < 7; ++j)
            acc[j] += xv * W[j * 64 + k];  // uniform -> s_load
    }
    float4* op = (float4*)(out + (size_t)r * 8);
    op[0] = make_float4(acc[0], acc[1], acc[2], acc[3]);
    op[1] = make_float4(acc[4], acc[5], acc[6], 0.f);
}

// ---------------- gather aggregation: bf16 table, fp32 accumulate ----------

// Lane map: slot = lane>>3 (8 edge slots), ch8 = lane&7 (uint4 = 8 bf16 ch).
__global__ __launch_bounds__(256) void gather64b(const int* __restrict__ off,
                                                 const unsigned int* __restrict__ csr_src,
                                                 const unsigned int* __restrict__ tb,
                                                 const float* __restrict__ b,
                                                 float* __restrict__ out,
                                                 int do_relu) {
    int node = blockIdx.x * 4 + (threadIdx.x >> 6);
    if (node >= N_NODES) return;
    const int lane = threadIdx.x & 63;
    const int slot = lane >> 3;
    const int ch8  = lane & 7;
    int e0 = off[node], e1 = off[node + 1];
    const uint4* t4 = (const uint4*)tb;
    float s[8] = {0.f, 0.f, 0.f, 0.f, 0.f, 0.f, 0.f, 0.f};
    for (int e = e0; e < e1; e += 16) {
        int i0 = e + slot;
        int i1 = e + 8 + slot;
        bool p0 = i0 < e1, p1 = i1 < e1;
        unsigned int a0 = csr_src[p0 ? i0 : e];
        unsigned int a1 = csr_src[p1 ? i1 : e];
        uint4 v0 = t4[(size_t)a0 * 8 + ch8];
        uint4 v1 = t4[(size_t)a1 * 8 + ch8];
        if (p0) {
            s[0] += __uint_as_float(v0.x << 16);
            s[1] += __uint_as_float(v0.x & 0xFFFF0000u);
            s[2] += __uint_as_float(v0.y << 16);
            s[3] += __uint_as_float(v0.y & 0xFFFF0000u);
            s[4] += __uint_as_float(v0.z << 16);
            s[5] += __uint_as_float(v0.z & 0xFFFF0000u);
            s[6] += __uint_as_float(v0.w << 16);
            s[7] += __uint_as_float(v0.w & 0xFFFF0000u);
        }
        if (p1) {
            s[0] += __uint_as_float(v1.x << 16);
            s[1] += __uint_as_float(v1.x & 0xFFFF0000u);
            s[2] += __uint_as_float(v1.y << 16);
            s[3] += __uint_as_float(v1.y & 0xFFFF0000u);
            s[4] += __uint_as_float(v1.z << 16);
            s[5] += __uint_as_float(v1.z & 0xFFFF0000u);
            s[6] += __uint_as_float(v1.w << 16);
            s[7] += __uint_as_float(v1.w & 0xFFFF0000u);
        }
    }
#pragma unroll
    for (int d = 8; d <= 32; d <<= 1) {
#pragma unroll
        for (int j = 0; j < 8; ++j) s[j] += __shfl_xor(s[j], d, 64);
    }
    if (lane < 8) {
        const float4 b0 = ((const float4*)b)[ch8 * 2];
        const float4 b1 = ((const float4*)b)[ch8 * 2 + 1];
        float4 r0, r1;
        r0.x = s[0] + b0.x; r0.y = s[1] + b0.y; r0.z = s[2] + b0.z; r0.w = s[3] + b0.w;
        r1.x = s[4] + b1.x; r1.y = s[5] + b1.y; r1.z = s[6] + b1.z; r1.w = s[7] + b1.w;
        if (do_relu) {
            r0.x = fmaxf(r0.x, 0.f); r0.y = fmaxf(r0.y, 0.f);
            r0.z = fmaxf(r0.z, 0.f); r0.w = fmaxf(r0.w, 0.f);
            r1.x = fmaxf(r1.x, 0.f); r1.y = fmaxf(r1.y, 0.f);
            r1.z = fmaxf(r1.z, 0.f); r1.w = fmaxf(r1.w, 0.f);
        }
        float4* orow = (float4*)(out + (size_t)node * 64 + ch8 * 8);
        orow[0] = r0;
        orow[1] = r1;
    }
}

// 7-ch gather + bias + log_softmax (fp32 t3). slot = lane>>1, h = lane&1.
__global__ __launch_bounds__(256) void gather7_lsm(const int* __restrict__ off,
                                                   const unsigned int* __restrict__ csr_src,
                                                   const float* __restrict__ t3,
                                                   const float* __restrict__ b,
                                                   float* __restrict__ out) {
    int node = blockIdx.x * 4 + (threadIdx.x >> 6);
    if (node >= N_NODES) return;
    const int lane = threadIdx.x & 63;
    const int slot = lane >> 1;
    const int h    = lane & 1;
    int e0 = off[node], e1 = off[node + 1];
    const float4* t4 = (const float4*)t3;
    float sx = 0.f, sy = 0.f, sz = 0.f, sw = 0.f;
    for (int e = e0 + slot; e < e1; e += 32) {
        unsigned int s = csr_src[e];
        float4 v = t4[(size_t)s * 2 + h];
        sx += v.x; sy += v.y; sz += v.z; sw += v.w;
    }
#pragma unroll
    for (int d = 2; d <= 32; d <<= 1) {
        sx += __shfl_xor(sx, d, 64); sy += __shfl_xor(sy, d, 64);
        sz += __shfl_xor(sz, d, 64); sw += __shfl_xor(sw, d, 64);
    }
    float z0 = sx + b[h * 4 + 0];
    float z1 = sy + b[h * 4 + 1];
    float z2 = sz + b[h * 4 + 2];
    float z3 = (h == 0) ? (sw + b[3]) : -1e30f;
    float m = fmaxf(fmaxf(z0, z1), fmaxf(z2, z3));
    m = fmaxf(m, __shfl_xor(m, 1, 64));
    float ex = __expf(z0 - m) + __expf(z1 - m) + __expf(z2 - m) + __expf(z3 - m);
    ex += __shfl_xor(ex, 1, 64);
    float l = m + __logf(ex);
    if (lane < 2) {
        float* o = out + (size_t)node * 7 + h * 4;
        o[0] = z0 - l; o[1] = z1 - l; o[2] = z2 - l;
        if (h == 0) o[3] = z3 - l;
    }
}

extern "C" void kernel_launch(void* const* d_in, const int* in_sizes, int n_in,
                              void* d_out, int out_size, void* d_ws, size_t ws_size,
                              hipStream_t stream) {
    const float* x  = (const float*)d_in[0];
    const int*   ei = (const int*)d_in[1];
    const float* W1 = (const float*)d_in[2];
    const float* b1 = (const float*)d_in[3];
    const float* W2 = (const float*)d_in[4];
    const float* b2 = (const float*)d_in[5];
    const float* W3 = (const float*)d_in[6];
    const float* b3 = (const float*)d_in[7];
    float* out = (float*)d_out;

    const int* src = ei;
    const int* dst = ei + N_EDGES;

    // workspace: A region (12.8 MB): phase-1 buckets (8.03 MB, dead after
    // build_csr) -> bf16 table (6.4 MB, layers 1-2) -> fp32 stride-8 t3.
    float* A = (float*)d_ws;                       // 12.8 MB
    float* B = A + (size_t)N_NODES * C;            // 12.8 MB (fp32 h buffer)
    unsigned int* csr = (unsigned int*)(B + (size_t)N_NODES * C);
    int* off     = (int*)(csr + N_EDGES);          // 50001
    int* gcursor = off + N_NODES + 8;              // 196
    unsigned int* buckets = (unsigned int*)A;      // aliases A
    unsigned int* Abf     = (unsigned int*)A;      // bf16 table view

    const int l64grid = (N_NODES + 63) / 64;       // 782 blocks x 4 waves
    const int l7grid  = (N_NODES + 127) / 128;     // 391
    const int ngrid   = (N_NODES + 3) / 4;         // 12500

    // ---- CSR build
    (void)hipMemsetAsync(gcursor, 0, NB * sizeof(int), stream);
    bin_kernel<<<(N_EDGES + CHUNK - 1) / CHUNK, 256, 0, stream>>>(src, dst, buckets, gcursor);
    build_csr<<<NB, 256, 0, stream>>>(buckets, gcursor, csr, off);

    // ---- layer 1 (A free after build_csr)
    linear64_bf16<<<l64grid, 256, 0, stream>>>(x, W1, Abf);
    gather64b<<<ngrid, 256, 0, stream>>>(off, csr, Abf, b1, B, 1);

    // ---- layer 2
    linear64_bf16<<<l64grid, 256, 0, stream>>>(B, W2, Abf);
    gather64b<<<ngrid, 256, 0, stream>>>(off, csr, Abf, b2, B, 1);

    // ---- layer 3 (fp32 staging, stride-8)
    linear7_rows<<<l7grid, 128, 0, stream>>>(B, W3, A);
    gather7_lsm<<<ngrid, 256, 0, stream>>>(off, csr, A, b3, out);
}

// Round 12
// 264.757 us; speedup vs baseline: 1.7850x; 1.1339x over previous
//
#include <hip/hip_runtime.h>
#include <math.h>

#define N_NODES 50000
#define N_EDGES 1600000
#define C 64
#define OUTC 7

#define NB 196         // coarse buckets: dst >> 8  (49999>>8 = 195)
#define BCAP 10240     // bucket capacity (mean 8192, sigma ~90)
#define CHUNK 4096     // edges per phase-1 workgroup

// fp32 -> bf16 (RNE), packed pair into u32 (lo = even channel, hi = odd)
__device__ __forceinline__ unsigned int pk_bf16(float a, float b) {
    unsigned int ua = __float_as_uint(a);
    ua = (ua + 0x7FFFu + ((ua >> 16) & 1u)) >> 16;
    unsigned int ub = __float_as_uint(b);
    ub = (ub + 0x7FFFu + ((ub >> 16) & 1u)) >> 16;
    return ua | (ub << 16);
}

// ---------------- CSR build, phase 1: coarse binning ----------------
// Pack edge as (dst<<16)|src (both < 65536). bucket = v >> 24 (= dst>>8).
__global__ __launch_bounds__(256) void bin_kernel(const int* __restrict__ src,
                                                  const int* __restrict__ dst,
                                                  unsigned int* __restrict__ buckets,
                                                  int* __restrict__ gcursor) {
    __shared__ unsigned int staged[CHUNK];          // 16 KB
    __shared__ int hist[NB], scanb[NB], cur[NB], baseb[NB];
    const int tid = threadIdx.x;
    const int base = blockIdx.x * CHUNK;
    int n = N_EDGES - base; if (n > CHUNK) n = CHUNK;  // multiple of 4

    for (int b = tid; b < NB; b += 256) { hist[b] = 0; cur[b] = 0; }
    __syncthreads();

    const int4* src4 = (const int4*)(src + base);
    const int4* dst4 = (const int4*)(dst + base);
    unsigned int v[16];
    int nv = n >> 2;
#pragma unroll
    for (int k = 0; k < 4; ++k) {
        int i4 = k * 256 + tid;
        if (i4 < nv) {
            int4 s4 = src4[i4];
            int4 d4 = dst4[i4];
            unsigned int d0 = (unsigned int)d4.x, d1 = (unsigned int)d4.y;
            unsigned int d2 = (unsigned int)d4.z, d3 = (unsigned int)d4.w;
            v[k * 4 + 0] = (d0 << 16) | (unsigned int)s4.x;
            v[k * 4 + 1] = (d1 << 16) | (unsigned int)s4.y;
            v[k * 4 + 2] = (d2 << 16) | (unsigned int)s4.z;
            v[k * 4 + 3] = (d3 << 16) | (unsigned int)s4.w;
            atomicAdd(&hist[d0 >> 8], 1);
            atomicAdd(&hist[d1 >> 8], 1);
            atomicAdd(&hist[d2 >> 8], 1);
            atomicAdd(&hist[d3 >> 8], 1);
        }
    }
    __syncthreads();
    if (tid == 0) {
        int run = 0;
        for (int b = 0; b < NB; ++b) { scanb[b] = run; run += hist[b]; }
    }
    __syncthreads();
#pragma unroll
    for (int k = 0; k < 4; ++k) {
        int i4 = k * 256 + tid;
        if (i4 < nv) {
#pragma unroll
            for (int q = 0; q < 4; ++q) {
                unsigned int w = v[k * 4 + q];
                int b = w >> 24;
                int p = scanb[b] + atomicAdd(&cur[b], 1);
                staged[p] = w;
            }
        }
    }
    __syncthreads();
    if (tid < NB) baseb[tid] = atomicAdd(&gcursor[tid], hist[tid]);
    __syncthreads();
    for (int i = tid; i < n; i += 256) {
        unsigned int w = staged[i];
        int b = w >> 24;
        buckets[(size_t)b * BCAP + baseb[b] + (i - scanb[b])] = w;
    }
}

// ---------------- CSR build, phase 2: per-bucket local CSR ----------------
__global__ __launch_bounds__(256) void build_csr(const unsigned int* __restrict__ buckets,
                                                 const int* __restrict__ gcursor,
                                                 unsigned int* __restrict__ csr,
                                                 int* __restrict__ off) {
    __shared__ int hist[256], part[256], offx[256], cur[256];
    __shared__ int gl[NB];
    __shared__ int s_cnt, s_base;
    const int tid = threadIdx.x;
    const int b = blockIdx.x;

    hist[tid] = 0;
    cur[tid] = 0;
    if (tid < NB) gl[tid] = gcursor[tid];
    __syncthreads();
    if (tid == 0) {
        int bs = 0;
        for (int i = 0; i < b; ++i) bs += gl[i];
        s_base = bs;
        s_cnt = gl[b];
    }
    __syncthreads();
    const int cnt = s_cnt;
    const int gbase = s_base;
    const unsigned int* bk = buckets + (size_t)b * BCAP;

    for (int i = tid; i < cnt; i += 256) {
        atomicAdd(&hist[(bk[i] >> 16) & 255], 1);
    }
    __syncthreads();
    part[tid] = hist[tid];
    __syncthreads();
    for (int d = 1; d < 256; d <<= 1) {
        int t = (tid >= d) ? part[tid - d] : 0;
        __syncthreads();
        part[tid] += t;
        __syncthreads();
    }
    offx[tid] = (tid == 0) ? 0 : part[tid - 1];
    __syncthreads();
    int node = b * 256 + tid;
    if (node < N_NODES) off[node] = gbase + offx[tid];
    if (b == NB - 1 && tid == 0) off[N_NODES] = gbase + cnt;
    for (int i = tid; i < cnt; i += 256) {
        unsigned int w = bk[i];
        int dl = (w >> 16) & 255;
        int p = offx[dl] + atomicAdd(&cur[dl], 1);
        csr[gbase + p] = w & 0xFFFFu;
    }
}

// ---------------- dense linears ----------------

// Block-level channel-group split: cg = blockIdx.x & 3 (SGPR-native,
// workgroup-uniform) owns channels [cg*16, cg*16+16); thread = row.
// W + cg*1024 is a plain GEP on the __restrict__ arg -> provenance intact ->
// s_load (K$). 784 blocks = 3136 waves (~12/CU). x rows read 4x (LLC-fed).
__global__ __launch_bounds__(256) void linear64_bf16(const float* __restrict__ x,
                                                     const float* __restrict__ W,
                                                     unsigned int* __restrict__ tb) {
    const int cg = blockIdx.x & 3;
    const int r = (blockIdx.x >> 2) * 256 + threadIdx.x;
    if (r >= N_NODES) return;
    float4 xr[16];
    const float4* xp = (const float4*)(x + (size_t)r * 64);
#pragma unroll
    for (int j = 0; j < 16; ++j) xr[j] = xp[j];
    const float* xf = (const float*)xr;

    const float* Wp = W + cg * 16 * 64;   // uniform GEP -> s_load
    unsigned int* orow = tb + (size_t)r * 32 + cg * 8;  // 8 u32 = 16 bf16
    for (int c0 = 0; c0 < 16; c0 += 8) {
        float acc[8] = {0.f, 0.f, 0.f, 0.f, 0.f, 0.f, 0.f, 0.f};
#pragma unroll
        for (int k = 0; k < 64; ++k) {
            float xv = xf[k];
#pragma unroll
            for (int j = 0; j < 8; ++j)
                acc[j] += xv * Wp[(c0 + j) * 64 + k];  // uniform -> s_load
        }
        uint4 w;
        w.x = pk_bf16(acc[0], acc[1]);
        w.y = pk_bf16(acc[2], acc[3]);
        w.z = pk_bf16(acc[4], acc[5]);
        w.w = pk_bf16(acc[6], acc[7]);
        ((uint4*)orow)[c0 >> 3] = w;
    }
}

// Thread-per-row, fully-uniform W3 (kernel arg) -> auto-scalarized s_loads.
// 448 FMA/thread; W3 = 1.75 KB, K$-resident. Writes stride-8 padded rows.
__global__ __launch_bounds__(128) void linear7_rows(const float* __restrict__ x,
                                                    const float* __restrict__ W,
                                                    float* __restrict__ out) {
    int r = blockIdx.x * 128 + threadIdx.x;
    if (r >= N_NODES) return;
    float4 xr[16];
    const float4* xp = (const float4*)(x + (size_t)r * 64);
#pragma unroll
    for (int j = 0; j < 16; ++j) xr[j] = xp[j];
    const float* xf = (const float*)xr;

    float acc[7] = {0.f, 0.f, 0.f, 0.f, 0.f, 0.f, 0.f};
#pragma unroll
    for (int k = 0; k < 64; ++k) {
        float xv = xf[k];
#pragma unroll
        for (int j = 0; j < 7; ++j)
            acc[j] += xv * W[j * 64 + k];  // uniform -> s_load
    }
    float4* op = (float4*)(out + (size_t)r * 8);
    op[0] = make_float4(acc[0], acc[1], acc[2], acc[3]);
    op[1] = make_float4(acc[4], acc[5], acc[6], 0.f);
}

// ---------------- gather aggregation: bf16 table, fp32 accumulate ----------

// Lane map: slot = lane>>3 (8 edge slots), ch8 = lane&7 (uint4 = 8 bf16 ch).
__global__ __launch_bounds__(256) void gather64b(const int* __restrict__ off,
                                                 const unsigned int* __restrict__ csr_src,
                                                 const unsigned int* __restrict__ tb,
                                                 const float* __restrict__ b,
                                                 float* __restrict__ out,
                                                 int do_relu) {
    int node = blockIdx.x * 4 + (threadIdx.x >> 6);
    if (node >= N_NODES) return;
    const int lane = threadIdx.x & 63;
    const int slot = lane >> 3;
    const int ch8  = lane & 7;
    int e0 = off[node], e1 = off[node + 1];
    const uint4* t4 = (const uint4*)tb;
    float s[8] = {0.f, 0.f, 0.f, 0.f, 0.f, 0.f, 0.f, 0.f};
    for (int e = e0; e < e1; e += 16) {
        int i0 = e + slot;
        int i1 = e + 8 + slot;
        bool p0 = i0 < e1, p1 = i1 < e1;
        unsigned int a0 = csr_src[p0 ? i0 : e];
        unsigned int a1 = csr_src[p1 ? i1 : e];
        uint4 v0 = t4[(size_t)a0 * 8 + ch8];
        uint4 v1 = t4[(size_t)a1 * 8 + ch8];
        if (p0) {
            s[0] += __uint_as_float(v0.x << 16);
            s[1] += __uint_as_float(v0.x & 0xFFFF0000u);
            s[2] += __uint_as_float(v0.y << 16);
            s[3] += __uint_as_float(v0.y & 0xFFFF0000u);
            s[4] += __uint_as_float(v0.z << 16);
            s[5] += __uint_as_float(v0.z & 0xFFFF0000u);
            s[6] += __uint_as_float(v0.w << 16);
            s[7] += __uint_as_float(v0.w & 0xFFFF0000u);
        }
        if (p1) {
            s[0] += __uint_as_float(v1.x << 16);
            s[1] += __uint_as_float(v1.x & 0xFFFF0000u);
            s[2] += __uint_as_float(v1.y << 16);
            s[3] += __uint_as_float(v1.y & 0xFFFF0000u);
            s[4] += __uint_as_float(v1.z << 16);
            s[5] += __uint_as_float(v1.z & 0xFFFF0000u);
            s[6] += __uint_as_float(v1.w << 16);
            s[7] += __uint_as_float(v1.w & 0xFFFF0000u);
        }
    }
#pragma unroll
    for (int d = 8; d <= 32; d <<= 1) {
#pragma unroll
        for (int j = 0; j < 8; ++j) s[j] += __shfl_xor(s[j], d, 64);
    }
    if (lane < 8) {
        const float4 b0 = ((const float4*)b)[ch8 * 2];
        const float4 b1 = ((const float4*)b)[ch8 * 2 + 1];
        float4 r0, r1;
        r0.x = s[0] + b0.x; r0.y = s[1] + b0.y; r0.z = s[2] + b0.z; r0.w = s[3] + b0.w;
        r1.x = s[4] + b1.x; r1.y = s[5] + b1.y; r1.z = s[6] + b1.z; r1.w = s[7] + b1.w;
        if (do_relu) {
            r0.x = fmaxf(r0.x, 0.f); r0.y = fmaxf(r0.y, 0.f);
            r0.z = fmaxf(r0.z, 0.f); r0.w = fmaxf(r0.w, 0.f);
            r1.x = fmaxf(r1.x, 0.f); r1.y = fmaxf(r1.y, 0.f);
            r1.z = fmaxf(r1.z, 0.f); r1.w = fmaxf(r1.w, 0.f);
        }
        float4* orow = (float4*)(out + (size_t)node * 64 + ch8 * 8);
        orow[0] = r0;
        orow[1] = r1;
    }
}

// 7-ch gather + bias + log_softmax (fp32 t3). slot = lane>>1, h = lane&1.
__global__ __launch_bounds__(256) void gather7_lsm(const int* __restrict__ off,
                                                   const unsigned int* __restrict__ csr_src,
                                                   const float* __restrict__ t3,
                                                   const float* __restrict__ b,
                                                   float* __restrict__ out) {
    int node = blockIdx.x * 4 + (threadIdx.x >> 6);
    if (node >= N_NODES) return;
    const int lane = threadIdx.x & 63;
    const int slot = lane >> 1;
    const int h    = lane & 1;
    int e0 = off[node], e1 = off[node + 1];
    const float4* t4 = (const float4*)t3;
    float sx = 0.f, sy = 0.f, sz = 0.f, sw = 0.f;
    for (int e = e0 + slot; e < e1; e += 32) {
        unsigned int s = csr_src[e];
        float4 v = t4[(size_t)s * 2 + h];
        sx += v.x; sy += v.y; sz += v.z; sw += v.w;
    }
#pragma unroll
    for (int d = 2; d <= 32; d <<= 1) {
        sx += __shfl_xor(sx, d, 64); sy += __shfl_xor(sy, d, 64);
        sz += __shfl_xor(sz, d, 64); sw += __shfl_xor(sw, d, 64);
    }
    float z0 = sx + b[h * 4 + 0];
    float z1 = sy + b[h * 4 + 1];
    float z2 = sz + b[h * 4 + 2];
    float z3 = (h == 0) ? (sw + b[3]) : -1e30f;
    float m = fmaxf(fmaxf(z0, z1), fmaxf(z2, z3));
    m = fmaxf(m, __shfl_xor(m, 1, 64));
    float ex = __expf(z0 - m) + __expf(z1 - m) + __expf(z2 - m) + __expf(z3 - m);
    ex += __shfl_xor(ex, 1, 64);
    float l = m + __logf(ex);
    if (lane < 2) {
        float* o = out + (size_t)node * 7 + h * 4;
        o[0] = z0 - l; o[1] = z1 - l; o[2] = z2 - l;
        if (h == 0) o[3] = z3 - l;
    }
}

extern "C" void kernel_launch(void* const* d_in, const int* in_sizes, int n_in,
                              void* d_out, int out_size, void* d_ws, size_t ws_size,
                              hipStream_t stream) {
    const float* x  = (const float*)d_in[0];
    const int*   ei = (const int*)d_in[1];
    const float* W1 = (const float*)d_in[2];
    const float* b1 = (const float*)d_in[3];
    const float* W2 = (const float*)d_in[4];
    const float* b2 = (const float*)d_in[5];
    const float* W3 = (const float*)d_in[6];
    const float* b3 = (const float*)d_in[7];
    float* out = (float*)d_out;

    const int* src = ei;
    const int* dst = ei + N_EDGES;

    // workspace: A region (12.8 MB): phase-1 buckets (8.03 MB, dead after
    // build_csr) -> bf16 table (6.4 MB, layers 1-2) -> fp32 stride-8 t3.
    float* A = (float*)d_ws;                       // 12.8 MB
    float* B = A + (size_t)N_NODES * C;            // 12.8 MB (fp32 h buffer)
    unsigned int* csr = (unsigned int*)(B + (size_t)N_NODES * C);
    int* off     = (int*)(csr + N_EDGES);          // 50001
    int* gcursor = off + N_NODES + 8;              // 196
    unsigned int* buckets = (unsigned int*)A;      // aliases A
    unsigned int* Abf     = (unsigned int*)A;      // bf16 table view

    const int l64grid = ((N_NODES + 255) / 256) * 4;  // 196 rowgroups x 4 cgs
    const int l7grid  = (N_NODES + 127) / 128;        // 391
    const int ngrid   = (N_NODES + 3) / 4;            // 12500

    // ---- CSR build
    (void)hipMemsetAsync(gcursor, 0, NB * sizeof(int), stream);
    bin_kernel<<<(N_EDGES + CHUNK - 1) / CHUNK, 256, 0, stream>>>(src, dst, buckets, gcursor);
    build_csr<<<NB, 256, 0, stream>>>(buckets, gcursor, csr, off);

    // ---- layer 1 (A free after build_csr)
    linear64_bf16<<<l64grid, 256, 0, stream>>>(x, W1, Abf);
    gather64b<<<ngrid, 256, 0, stream>>>(off, csr, Abf, b1, B, 1);

    // ---- layer 2
    linear64_bf16<<<l64grid, 256, 0, stream>>>(B, W2, Abf);
    gather64b<<<ngrid, 256, 0, stream>>>(off, csr, Abf, b2, B, 1);

    // ---- layer 3 (fp32 staging, stride-8)
    linear7_rows<<<l7grid, 128, 0, stream>>>(B, W3, A);
    gather7_lsm<<<ngrid, 256, 0, stream>>>(off, csr, A, b3, out);
}